// Round 10
// baseline (720.350 us; speedup 1.0000x reference)
//
#include <hip/hip_runtime.h>

#define N 50000
#define E 800000
#define H 128
#define G 64
#define OUTC 10
#define L 6
#define EPS 1e-5f
#define SLOTS 64   // fixed bucket capacity; deg ~ Poisson(16), P(deg>64) ~ 2e-18
#define GCHUNK 32  // gather channel-chunk: N*GCHUNK*2B = 3.2MB < 4MB per-XCD L2

typedef unsigned short ushort_t;
typedef __attribute__((ext_vector_type(8))) short short8;
typedef __attribute__((ext_vector_type(8))) unsigned short ushort8;
typedef __attribute__((ext_vector_type(4))) float floatx4;

__device__ __forceinline__ void atomAddF(float* p, float v) {
  unsafeAtomicAdd(p, v);   // hw global_atomic_add_f32 on gfx950
}

__device__ __forceinline__ unsigned short f2bf(float f) {
  unsigned u = __float_as_uint(f);
  unsigned r = (u + 0x7FFF + ((u >> 16) & 1)) >> 16;  // RNE
  return (unsigned short)r;
}
__device__ __forceinline__ float bf2f(unsigned short b) {
  return __uint_as_float(((unsigned)b) << 16);
}

// ---------------- merged init: zero | weight-transpose prep | graph counts ----------
// block ranges: [0, ZB) zero, [ZB, ZB+PB) prep, last block = cnt binary search
__global__ __launch_bounds__(256) void init_kernel(
    int* __restrict__ zerop, int zero_words, int ZB,
    const float* __restrict__ convW, ushort_t* __restrict__ WT,
    const int* __restrict__ batch, float* __restrict__ cntg)
{
  __shared__ int lb[G + 1];
  int b = blockIdx.x;
  if (b < ZB) {
    int i = b * 256 + threadIdx.x;
    if (i < zero_words) zerop[i] = 0;
  } else if (b < ZB + (L * H * H) / 256) {
    int j = (b - ZB) * 256 + threadIdx.x;   // j < L*H*H (exact multiple of 256)
    int l = j >> 14, r = j & 16383;         // H*H = 16384
    int n = r >> 7, k = r & 127;
    WT[j] = f2bf(convW[l * 16384 + k * 128 + n]);
  } else {
    int t = threadIdx.x;
    if (t <= G) {
      int lo = 0, hi = N;
      while (lo < hi) { int m = (lo + hi) >> 1; if (batch[m] < t) lo = m + 1; else hi = m; }
      lb[t] = lo;
    }
    __syncthreads();
    if (t < G) cntg[t] = (float)(lb[t + 1] - lb[t]);
  }
}

// one-pass bucket CSR build (ushort entries: N=50000 < 65536)
// accepted floor ~50us: traffic = 1 line-event per edge (padding probe was null)
__global__ void csr_fill_kernel(const int* __restrict__ src, const int* __restrict__ dst,
                                int* __restrict__ cnt, ushort_t* __restrict__ csru) {
  int e = blockIdx.x * blockDim.x + threadIdx.x;
  if (e < E) {
    int d = dst[e];
    int pos = atomicAdd(&cnt[d], 1);
    if (pos < SLOTS) csru[(d << 6) + pos] = (ushort_t)src[e];
  }
}

__global__ void dinv_kernel(const int* __restrict__ cnt, float* __restrict__ dinv) {
  int n = blockIdx.x * blockDim.x + threadIdx.x;
  if (n < N) dinv[n] = rsqrtf((float)(cnt[n] + 1));
}

// ---------------- MFMA GEMM: hWs[row] = dinv[row] * (f(A)@W)[row], bf16 ----------------
// OPERAND-SWAPPED: mfma(Wfrag, nodefrag) -> D[ch][node]; each thread holds 4
// CONSECUTIVE channels of ONE node -> ushort4 (8B) stores, 8 per thread.
// A source: Af (f32, layer 0) or Ab (bf16, layers 1..5); f = identity or BN+ReLU.
__global__ __launch_bounds__(256) void gemm_mfma_kernel(
    const ushort_t* __restrict__ Ab, const float* __restrict__ Af,
    const ushort_t* __restrict__ WT,
    const float* __restrict__ dinv, ushort_t* __restrict__ hWs,
    const float* __restrict__ bnsums, const float* __restrict__ gamma,
    const float* __restrict__ beta)
{
  const int tid = threadIdx.x;
  const int wave = tid >> 6, lane = tid & 63;
  const int quad = lane >> 4, m = lane & 15;
  const int row0 = blockIdx.x * 64 + wave * 16;
  const int arow = min(row0 + m, N - 1);
  const float invN = 1.0f / (float)N;

  short8 nfrag[4];   // node-row fragments (B operand after swap)
  if (Af) {
    // layer 0: read f32 x directly, convert RNE in-register
#pragma unroll
    for (int kc = 0; kc < 4; ++kc) {
      const float* p = &Af[arow * H + kc * 32 + quad * 8];
      float4 f0 = *(const float4*)p;
      float4 f1 = *(const float4*)(p + 4);
      short8 a;
      a[0] = (short)f2bf(f0.x); a[1] = (short)f2bf(f0.y);
      a[2] = (short)f2bf(f0.z); a[3] = (short)f2bf(f0.w);
      a[4] = (short)f2bf(f1.x); a[5] = (short)f2bf(f1.y);
      a[6] = (short)f2bf(f1.z); a[7] = (short)f2bf(f1.w);
      nfrag[kc] = a;
    }
  } else {
#pragma unroll
    for (int kc = 0; kc < 4; ++kc) {
      ushort8 raw = *(const ushort8*)&Ab[arow * H + kc * 32 + quad * 8];
      if (bnsums) {
        const int k0 = kc * 32 + quad * 8;
#pragma unroll
        for (int j = 0; j < 8; ++j) {
          float s = bnsums[k0 + j], q = bnsums[128 + k0 + j];
          float mu = s * invN;
          float var = q * invN - mu * mu;
          float rs = rsqrtf(var + EPS);
          float sc = gamma[k0 + j] * rs;
          float sh = beta[k0 + j] - mu * sc;
          raw[j] = f2bf(fmaxf(bf2f(raw[j]) * sc + sh, 0.f));
        }
      }
      short8 a;
#pragma unroll
      for (int j = 0; j < 8; ++j) a[j] = (short)raw[j];
      nfrag[kc] = a;
    }
  }

  const int node = row0 + m;
  const float dv = (node < N) ? dinv[node] : 0.f;

  const short* WTs = (const short*)WT;
#pragma unroll
  for (int nt = 0; nt < 8; ++nt) {
    floatx4 acc = {0.f, 0.f, 0.f, 0.f};
#pragma unroll
    for (int kc = 0; kc < 4; ++kc) {
      short8 wfrag = *(const short8*)&WTs[(nt * 16 + m) * H + kc * 32 + quad * 8];
      acc = __builtin_amdgcn_mfma_f32_16x16x32_bf16(wfrag, nfrag[kc], acc, 0, 0, 0);
    }
    // D[ch = nt*16 + quad*4 + i][node = lane&15]
    if (node < N) {
      ushort4 o;
      o.x = f2bf(acc[0] * dv);
      o.y = f2bf(acc[1] * dv);
      o.z = f2bf(acc[2] * dv);
      o.w = f2bf(acc[3] * dv);
      *(ushort4*)&hWs[node * H + nt * 16 + quad * 4] = o;   // 8B aligned
    }
  }
}

// ---------------- CSR gather, channel-chunked for L2 residency ----------------
// Pass computes channels [c0, c0+32) for ALL nodes: hWs column-slice footprint
// = N*32*2B = 3.2MB < 4MB per-XCD L2 -> row-chunk reads become L2 hits.
// 8 lanes/node x 4 channels (ushort4 = 8B); 64B/row-chunk per 8-lane group.
// 2-batch software pipeline + mask-predicated tails (proven round 7/8 body).
__device__ __forceinline__ void addRow(float acc[4], ushort4 u) {
  acc[0] += bf2f(u.x); acc[1] += bf2f(u.y);
  acc[2] += bf2f(u.z); acc[3] += bf2f(u.w);
}
__device__ __forceinline__ void addRowM(float acc[4], ushort4 u, float m) {
  acc[0] += m * bf2f(u.x); acc[1] += m * bf2f(u.y);
  acc[2] += m * bf2f(u.z); acc[3] += m * bf2f(u.w);
}

#define LOAD8_4(dst, idx)                                           \
  ushort4 dst##0 = *(const ushort4*)&hWs[(int)idx[0] * H + c4];     \
  ushort4 dst##1 = *(const ushort4*)&hWs[(int)idx[1] * H + c4];     \
  ushort4 dst##2 = *(const ushort4*)&hWs[(int)idx[2] * H + c4];     \
  ushort4 dst##3 = *(const ushort4*)&hWs[(int)idx[3] * H + c4];     \
  ushort4 dst##4 = *(const ushort4*)&hWs[(int)idx[4] * H + c4];     \
  ushort4 dst##5 = *(const ushort4*)&hWs[(int)idx[5] * H + c4];     \
  ushort4 dst##6 = *(const ushort4*)&hWs[(int)idx[6] * H + c4];     \
  ushort4 dst##7 = *(const ushort4*)&hWs[(int)idx[7] * H + c4];

__global__ __launch_bounds__(256) void gather_kernel(
    const ushort_t* __restrict__ hWs, const ushort_t* __restrict__ csru,
    const int* __restrict__ cnt, const float* __restrict__ dinv,
    const float* __restrict__ bias, ushort_t* __restrict__ aggb, int c0)
{
  int t = blockIdx.x * 256 + threadIdx.x;
  int n = t >> 3;                       // 8 lanes per node
  if (n >= N) return;
  int c4 = c0 + (t & 7) * 4;            // 4 channels per lane within [c0, c0+32)

  const int base = n << 6;
  const int deg = min(cnt[n], SLOTS);

  ushort4 us = *(const ushort4*)&hWs[n * H + c4];
  float acc[4];
  acc[0] = bf2f(us.x); acc[1] = bf2f(us.y);
  acc[2] = bf2f(us.z); acc[3] = bf2f(us.w);

  const int nbat = (deg + 7) >> 3;   // 0..8 batches; only last batch partial
  int b = 0;
  for (; b + 2 <= nbat; b += 2) {
    const int eA = b << 3, eB = eA + 8;
    ushort8 idxA = *(const ushort8*)&csru[base + eA];
    ushort8 idxB = *(const ushort8*)&csru[base + eB];
    LOAD8_4(a, idxA)
    LOAD8_4(r, idxB)
    // batch A (index b <= nbat-2) is always full
    addRow(acc, a0); addRow(acc, a1); addRow(acc, a2); addRow(acc, a3);
    addRow(acc, a4); addRow(acc, a5); addRow(acc, a6); addRow(acc, a7);
    if (eB + 8 <= deg) {
      addRow(acc, r0); addRow(acc, r1); addRow(acc, r2); addRow(acc, r3);
      addRow(acc, r4); addRow(acc, r5); addRow(acc, r6); addRow(acc, r7);
    } else {
      addRowM(acc, r0, (eB + 0 < deg) ? 1.f : 0.f);
      addRowM(acc, r1, (eB + 1 < deg) ? 1.f : 0.f);
      addRowM(acc, r2, (eB + 2 < deg) ? 1.f : 0.f);
      addRowM(acc, r3, (eB + 3 < deg) ? 1.f : 0.f);
      addRowM(acc, r4, (eB + 4 < deg) ? 1.f : 0.f);
      addRowM(acc, r5, (eB + 5 < deg) ? 1.f : 0.f);
      addRowM(acc, r6, (eB + 6 < deg) ? 1.f : 0.f);
      addRowM(acc, r7, (eB + 7 < deg) ? 1.f : 0.f);
    }
  }
  if (b < nbat) {  // leftover single batch (possibly partial)
    const int eA = b << 3;
    ushort8 idxA = *(const ushort8*)&csru[base + eA];
    LOAD8_4(a, idxA)
    if (eA + 8 <= deg) {
      addRow(acc, a0); addRow(acc, a1); addRow(acc, a2); addRow(acc, a3);
      addRow(acc, a4); addRow(acc, a5); addRow(acc, a6); addRow(acc, a7);
    } else {
      addRowM(acc, a0, (eA + 0 < deg) ? 1.f : 0.f);
      addRowM(acc, a1, (eA + 1 < deg) ? 1.f : 0.f);
      addRowM(acc, a2, (eA + 2 < deg) ? 1.f : 0.f);
      addRowM(acc, a3, (eA + 3 < deg) ? 1.f : 0.f);
      addRowM(acc, a4, (eA + 4 < deg) ? 1.f : 0.f);
      addRowM(acc, a5, (eA + 5 < deg) ? 1.f : 0.f);
      addRowM(acc, a6, (eA + 6 < deg) ? 1.f : 0.f);
      addRowM(acc, a7, (eA + 7 < deg) ? 1.f : 0.f);
    }
  }

  float dn = dinv[n];
  float4 bb = *(const float4*)&bias[c4];   // 16B aligned: c4 % 4 == 0
  ushort4 o;
  o.x = f2bf(acc[0] * dn + bb.x);
  o.y = f2bf(acc[1] * dn + bb.y);
  o.z = f2bf(acc[2] * dn + bb.z);
  o.w = f2bf(acc[3] * dn + bb.w);
  *(ushort4*)&aggb[n * H + c4] = o;
}

// ---------------- batchnorm stats over bf16 agg (vectorized ushort8 loads) ----------
// 391 blocks x 128 rows; thread: cg=tid&15 (8 channels), nn=tid>>4 (row in 16-group)
// reduce: shfl over nn-in-wave (x16, x32) -> LDS across 4 waves -> 256 atomics/block
__global__ __launch_bounds__(256) void bn_stats_kernel(
    const ushort_t* __restrict__ a, float* __restrict__ sums)
{
  __shared__ float redS[4 * 128], redQ[4 * 128];
  int tid = threadIdx.x;
  int cg = tid & 15, nn = tid >> 4;
  int c8 = cg * 8;
  int r0 = blockIdx.x * 128;
  float s[8], q[8];
#pragma unroll
  for (int j = 0; j < 8; ++j) { s[j] = 0.f; q[j] = 0.f; }
#pragma unroll
  for (int i = 0; i < 8; ++i) {
    int r = r0 + i * 16 + nn;
    if (r < N) {
      ushort8 u = *(const ushort8*)&a[r * H + c8];
#pragma unroll
      for (int j = 0; j < 8; ++j) { float v = bf2f(u[j]); s[j] += v; q[j] += v * v; }
    }
  }
  int wave = tid >> 6, lane = tid & 63;
#pragma unroll
  for (int j = 0; j < 8; ++j) {
    s[j] += __shfl_xor(s[j], 16); s[j] += __shfl_xor(s[j], 32);
    q[j] += __shfl_xor(q[j], 16); q[j] += __shfl_xor(q[j], 32);
  }
  if (lane < 16) {
#pragma unroll
    for (int j = 0; j < 8; ++j) {
      redS[wave * 128 + lane * 8 + j] = s[j];
      redQ[wave * 128 + lane * 8 + j] = q[j];
    }
  }
  __syncthreads();
  if (tid < 128) {
    float v = redS[tid] + redS[128 + tid] + redS[256 + tid] + redS[384 + tid];
    atomAddF(&sums[tid], v);
  } else {
    int t2 = tid - 128;
    float v = redQ[t2] + redQ[128 + t2] + redQ[256 + t2] + redQ[384 + t2];
    atomAddF(&sums[128 + t2], v);
  }
}

// ---------------- global mean pool: chunked run-length accumulate (batch sorted) --------
__global__ __launch_bounds__(256) void pool_kernel(
    const ushort_t* __restrict__ h, const int* __restrict__ batch,
    float* __restrict__ pooled /* pre-zeroed */)
{
  int r0 = blockIdx.x * 128;
  int rend = min(r0 + 128, N);
  int c = threadIdx.x & 127, half = threadIdx.x >> 7;
  float acc = 0.f;
  int curg = -1;
  for (int r = r0 + half; r < rend; r += 2) {
    int g = batch[r];
    if (g != curg) {
      if (curg >= 0) atomAddF(&pooled[curg * H + c], acc);
      acc = 0.f; curg = g;
    }
    acc += bf2f(h[r * H + c]);
  }
  if (curg >= 0) atomAddF(&pooled[curg * H + c], acc);
}

// ---------------- head (split, multi-block: latency-hiding via 32-64 blocks) ----------
__global__ void head1_kernel(const float* __restrict__ pooled, const float* __restrict__ cntg,
                             const float* __restrict__ W1, const float* __restrict__ b1,
                             float* __restrict__ z1)
{
  int t = blockIdx.x * 256 + threadIdx.x;  // 8192
  int g = t >> 7, c = t & 127;
  float s = 0.f;
  for (int k = 0; k < H; ++k) s += pooled[g * H + k] * W1[k * H + c];
  z1[t] = s / fmaxf(cntg[g], 1.0f) + b1[c];
}

__global__ void head_bn_kernel(float* __restrict__ z1,
                               const float* __restrict__ gamma, const float* __restrict__ beta)
{
  int c = threadIdx.x;  // 128 threads
  float s = 0.f, q = 0.f;
  for (int g = 0; g < G; ++g) { float v = z1[g * H + c]; s += v; q += v * v; }
  float mu = s / (float)G;
  float var = q / (float)G - mu * mu;
  float rs = rsqrtf(var + EPS);
  float ga = gamma[c], be = beta[c];
  for (int g = 0; g < G; ++g) {
    float v = z1[g * H + c];
    z1[g * H + c] = fmaxf((v - mu) * rs * ga + be, 0.f);
  }
}

__global__ void head2_kernel(const float* __restrict__ z1, const float* __restrict__ W2,
                             const float* __restrict__ b2, float* __restrict__ z2)
{
  int t = blockIdx.x * 256 + threadIdx.x;  // 8192
  int g = t >> 7, c = t & 127;
  float s = b2[c];
  for (int k = 0; k < H; ++k) s += z1[g * H + k] * W2[k * H + c];
  z2[t] = fmaxf(s, 0.f);
}

__global__ void head3_kernel(const float* __restrict__ z2, const float* __restrict__ W3,
                             const float* __restrict__ b3, float* __restrict__ out)
{
  int t = blockIdx.x * 256 + threadIdx.x;
  if (t < G * OUTC) {
    int g = t / OUTC, o = t % OUTC;
    float s = b3[o];
    for (int k = 0; k < H; ++k) s += z2[g * H + k] * W3[k * OUTC + o];
    out[t] = s;
  }
}

extern "C" void kernel_launch(void* const* d_in, const int* in_sizes, int n_in,
                              void* d_out, int out_size, void* d_ws, size_t ws_size,
                              hipStream_t stream) {
  const float* x     = (const float*)d_in[0];
  const int*   ei    = (const int*)d_in[1];
  const int*   srcp  = ei;
  const int*   dstp  = ei + E;
  const int*   batch = (const int*)d_in[2];
  const float* convW = (const float*)d_in[3];
  const float* convb = (const float*)d_in[4];
  const float* bng   = (const float*)d_in[5];
  const float* bnb   = (const float*)d_in[6];
  const float* W1    = (const float*)d_in[7];
  const float* b1    = (const float*)d_in[8];
  const float* hg    = (const float*)d_in[9];
  const float* hb    = (const float*)d_in[10];
  const float* W2    = (const float*)d_in[11];
  const float* b2    = (const float*)d_in[12];
  const float* W3    = (const float*)d_in[13];
  const float* b3    = (const float*)d_in[14];
  float* out = (float*)d_out;

  const size_t NH2 = (size_t)N * H / 2;            // bf16 buffer size in float units
  float*    ws     = (float*)d_ws;
  ushort_t* aggb   = (ushort_t*)ws;                // N*H bf16  (16B aligned)
  ushort_t* hWs    = (ushort_t*)(ws + NH2);        // N*H bf16
  ushort_t* WT     = (ushort_t*)(ws + 2 * NH2);    // L*H*H bf16 (49152 floats)
  float*    dinv   = ws + 2 * NH2 + (L * H * H / 2);  // N
  ushort_t* csru   = (ushort_t*)(dinv + N);        // N*SLOTS ushort (6.4 MB)
  int*      cnt    = (int*)(csru + (size_t)N * SLOTS); // N   <- zero region start
  float*    bnsums = (float*)(cnt + N);            // (L-1)*256
  float*    pooled = bnsums + (L - 1) * 256;       // G*H <- zero region end
  float*    cntg   = pooled + G * H;               // G
  float*    z1     = cntg + G;                     // G*H
  float*    z2     = z1 + G * H;                   // G*H

  const int zero_words = N + (L - 1) * 256 + G * H;
  const int ZB = (zero_words + 255) / 256;
  const int PB = (L * H * H) / 256;   // 384, exact
  init_kernel<<<ZB + PB + 1, 256, 0, stream>>>(cnt, zero_words, ZB, convW, WT, batch, cntg);
  csr_fill_kernel<<<(E + 255) / 256, 256, 0, stream>>>(srcp, dstp, cnt, csru);
  dinv_kernel<<<(N + 255) / 256, 256, 0, stream>>>(cnt, dinv);

  const int GB = (N * 8 + 255) / 256;   // 1563 blocks per channel chunk
  for (int l = 0; l < L; ++l) {
    const ushort_t* Ab = (l == 0) ? nullptr : aggb;
    const float*    Af = (l == 0) ? x : nullptr;
    const float* bs = (l == 0) ? nullptr : bnsums + (l - 1) * 256;
    const float* ga = (l == 0) ? nullptr : bng + (size_t)(l - 1) * H;
    const float* be = (l == 0) ? nullptr : bnb + (size_t)(l - 1) * H;
    gemm_mfma_kernel<<<(N + 63) / 64, 256, 0, stream>>>(
        Ab, Af, WT + (size_t)l * H * H, dinv, hWs, bs, ga, be);
    for (int c0 = 0; c0 < H; c0 += GCHUNK)
      gather_kernel<<<GB, 256, 0, stream>>>(
          hWs, csru, cnt, dinv, convb + (size_t)l * H, aggb, c0);
    if (l < L - 1)
      bn_stats_kernel<<<(N + 127) / 128, 256, 0, stream>>>(aggb, bnsums + l * 256);
  }

  pool_kernel<<<(N + 127) / 128, 256, 0, stream>>>(aggb, batch, pooled);
  head1_kernel<<<32, 256, 0, stream>>>(pooled, cntg, W1, b1, z1);
  head_bn_kernel<<<1, 128, 0, stream>>>(z1, hg, hb);
  head2_kernel<<<32, 256, 0, stream>>>(z1, W2, b2, z2);
  head3_kernel<<<3, 256, 0, stream>>>(z2, W3, b3, out);
}

// Round 11
// 587.953 us; speedup vs baseline: 1.2252x; 1.2252x over previous
//
#include <hip/hip_runtime.h>

#define N 50000
#define E 800000
#define H 128
#define G 64
#define OUTC 10
#define L 6
#define EPS 1e-5f
#define SLOTS 64     // fixed bucket capacity; deg ~ Poisson(16), P(deg>64) ~ 2e-18
#define NPHASE 4     // csr dst-range phases; slice = 12500*128B = 1.6MB < 4MB L2

typedef unsigned short ushort_t;
typedef __attribute__((ext_vector_type(8))) short short8;
typedef __attribute__((ext_vector_type(8))) unsigned short ushort8;
typedef __attribute__((ext_vector_type(4))) float floatx4;

__device__ __forceinline__ void atomAddF(float* p, float v) {
  unsafeAtomicAdd(p, v);   // hw global_atomic_add_f32 on gfx950
}

__device__ __forceinline__ unsigned short f2bf(float f) {
  unsigned u = __float_as_uint(f);
  unsigned r = (u + 0x7FFF + ((u >> 16) & 1)) >> 16;  // RNE
  return (unsigned short)r;
}
__device__ __forceinline__ float bf2f(unsigned short b) {
  return __uint_as_float(((unsigned)b) << 16);
}

// ---------------- merged init: zero | weight-transpose prep | graph counts ----------
// block ranges: [0, ZB) zero, [ZB, ZB+PB) prep, last block = cnt binary search
__global__ __launch_bounds__(256) void init_kernel(
    int* __restrict__ zerop, int zero_words, int ZB,
    const float* __restrict__ convW, ushort_t* __restrict__ WT,
    const int* __restrict__ batch, float* __restrict__ cntg)
{
  __shared__ int lb[G + 1];
  int b = blockIdx.x;
  if (b < ZB) {
    int i = b * 256 + threadIdx.x;
    if (i < zero_words) zerop[i] = 0;
  } else if (b < ZB + (L * H * H) / 256) {
    int j = (b - ZB) * 256 + threadIdx.x;   // j < L*H*H (exact multiple of 256)
    int l = j >> 14, r = j & 16383;         // H*H = 16384
    int n = r >> 7, k = r & 127;
    WT[j] = f2bf(convW[l * 16384 + k * 128 + n]);
  } else {
    int t = threadIdx.x;
    if (t <= G) {
      int lo = 0, hi = N;
      while (lo < hi) { int m = (lo + hi) >> 1; if (batch[m] < t) lo = m + 1; else hi = m; }
      lb[t] = lo;
    }
    __syncthreads();
    if (t < G) cntg[t] = (float)(lb[t + 1] - lb[t]);
  }
}

// dst-range-phased bucket CSR build (ushort entries).
// Phase p touches only csru/cnt for dst in [lo,hi): live write slice 1.6MB < L2.
// Probe: if L2 absorbs localized partial-line stores, WRITE_SIZE collapses.
// dst array re-scan is L3-resident (measured FETCH ~= dst size).
__global__ void csr_fill_phase_kernel(const int* __restrict__ src,
                                      const int* __restrict__ dst,
                                      int* __restrict__ cnt, ushort_t* __restrict__ csru,
                                      int lo, int hi) {
  int e = blockIdx.x * blockDim.x + threadIdx.x;
  if (e < E) {
    int d = dst[e];
    if (d >= lo && d < hi) {
      int pos = atomicAdd(&cnt[d], 1);
      if (pos < SLOTS) csru[(d << 6) + pos] = (ushort_t)src[e];
    }
  }
}

// ---------------- MFMA GEMM: hWs[row] = dinv[row] * (f(A)@W)[row], bf16 ----------------
// OPERAND-SWAPPED: mfma(Wfrag, nodefrag) -> D[ch][node]; each thread holds 4
// CONSECUTIVE channels of ONE node -> ushort4 (8B) stores, 8 per thread.
// dinv inlined: dv = rsqrt(cnt[node]+1) (dinv kernel/array removed).
// A source: Af (f32, layer 0) or Ab (bf16, layers 1..5); f = identity or BN+ReLU.
__global__ __launch_bounds__(256) void gemm_mfma_kernel(
    const ushort_t* __restrict__ Ab, const float* __restrict__ Af,
    const ushort_t* __restrict__ WT,
    const int* __restrict__ cnt, ushort_t* __restrict__ hWs,
    const float* __restrict__ bnsums, const float* __restrict__ gamma,
    const float* __restrict__ beta)
{
  const int tid = threadIdx.x;
  const int wave = tid >> 6, lane = tid & 63;
  const int quad = lane >> 4, m = lane & 15;
  const int row0 = blockIdx.x * 64 + wave * 16;
  const int arow = min(row0 + m, N - 1);
  const float invN = 1.0f / (float)N;

  short8 nfrag[4];   // node-row fragments (B operand after swap)
  if (Af) {
    // layer 0: read f32 x directly, convert RNE in-register
#pragma unroll
    for (int kc = 0; kc < 4; ++kc) {
      const float* p = &Af[arow * H + kc * 32 + quad * 8];
      float4 f0 = *(const float4*)p;
      float4 f1 = *(const float4*)(p + 4);
      short8 a;
      a[0] = (short)f2bf(f0.x); a[1] = (short)f2bf(f0.y);
      a[2] = (short)f2bf(f0.z); a[3] = (short)f2bf(f0.w);
      a[4] = (short)f2bf(f1.x); a[5] = (short)f2bf(f1.y);
      a[6] = (short)f2bf(f1.z); a[7] = (short)f2bf(f1.w);
      nfrag[kc] = a;
    }
  } else {
#pragma unroll
    for (int kc = 0; kc < 4; ++kc) {
      ushort8 raw = *(const ushort8*)&Ab[arow * H + kc * 32 + quad * 8];
      if (bnsums) {
        const int k0 = kc * 32 + quad * 8;
#pragma unroll
        for (int j = 0; j < 8; ++j) {
          float s = bnsums[k0 + j], q = bnsums[128 + k0 + j];
          float mu = s * invN;
          float var = q * invN - mu * mu;
          float rs = rsqrtf(var + EPS);
          float sc = gamma[k0 + j] * rs;
          float sh = beta[k0 + j] - mu * sc;
          raw[j] = f2bf(fmaxf(bf2f(raw[j]) * sc + sh, 0.f));
        }
      }
      short8 a;
#pragma unroll
      for (int j = 0; j < 8; ++j) a[j] = (short)raw[j];
      nfrag[kc] = a;
    }
  }

  const int node = row0 + m;
  const float dv = (node < N) ? rsqrtf((float)(cnt[node] + 1)) : 0.f;

  const short* WTs = (const short*)WT;
#pragma unroll
  for (int nt = 0; nt < 8; ++nt) {
    floatx4 acc = {0.f, 0.f, 0.f, 0.f};
#pragma unroll
    for (int kc = 0; kc < 4; ++kc) {
      short8 wfrag = *(const short8*)&WTs[(nt * 16 + m) * H + kc * 32 + quad * 8];
      acc = __builtin_amdgcn_mfma_f32_16x16x32_bf16(wfrag, nfrag[kc], acc, 0, 0, 0);
    }
    // D[ch = nt*16 + quad*4 + i][node = lane&15]
    if (node < N) {
      ushort4 o;
      o.x = f2bf(acc[0] * dv);
      o.y = f2bf(acc[1] * dv);
      o.z = f2bf(acc[2] * dv);
      o.w = f2bf(acc[3] * dv);
      *(ushort4*)&hWs[node * H + nt * 16 + quad * 4] = o;   // 8B aligned
    }
  }
}

// ---------------- CSR gather, 32 lanes/node + 2-batch software pipeline -------------
// (round-8 proven body; best measured config)
// aggb[n] = bf16( dinv[n]*(sum_e hWs[src_e] + hWs[n]) + bias ), dinv inlined.
// 32 lanes per node, 4 channels (ushort4 = 8B) per lane; grid exact (N*32/256).
__device__ __forceinline__ void addRow(float acc[4], ushort4 u) {
  acc[0] += bf2f(u.x); acc[1] += bf2f(u.y);
  acc[2] += bf2f(u.z); acc[3] += bf2f(u.w);
}
__device__ __forceinline__ void addRowM(float acc[4], ushort4 u, float m) {
  acc[0] += m * bf2f(u.x); acc[1] += m * bf2f(u.y);
  acc[2] += m * bf2f(u.z); acc[3] += m * bf2f(u.w);
}

#define LOAD8_4(dst, idx)                                           \
  ushort4 dst##0 = *(const ushort4*)&hWs[(int)idx[0] * H + c4];     \
  ushort4 dst##1 = *(const ushort4*)&hWs[(int)idx[1] * H + c4];     \
  ushort4 dst##2 = *(const ushort4*)&hWs[(int)idx[2] * H + c4];     \
  ushort4 dst##3 = *(const ushort4*)&hWs[(int)idx[3] * H + c4];     \
  ushort4 dst##4 = *(const ushort4*)&hWs[(int)idx[4] * H + c4];     \
  ushort4 dst##5 = *(const ushort4*)&hWs[(int)idx[5] * H + c4];     \
  ushort4 dst##6 = *(const ushort4*)&hWs[(int)idx[6] * H + c4];     \
  ushort4 dst##7 = *(const ushort4*)&hWs[(int)idx[7] * H + c4];

__global__ __launch_bounds__(256) void gather_kernel(
    const ushort_t* __restrict__ hWs, const ushort_t* __restrict__ csru,
    const int* __restrict__ cnt,
    const float* __restrict__ bias, ushort_t* __restrict__ aggb)
{
  int t = blockIdx.x * 256 + threadIdx.x;
  int n = t >> 5, c4 = (t & 31) * 4;

  const int base = n << 6;
  const int cn = cnt[n];
  const int deg = min(cn, SLOTS);

  ushort4 us = *(const ushort4*)&hWs[n * H + c4];
  float acc[4];
  acc[0] = bf2f(us.x); acc[1] = bf2f(us.y);
  acc[2] = bf2f(us.z); acc[3] = bf2f(us.w);

  const int nbat = (deg + 7) >> 3;   // 0..8 batches; only last batch partial
  int b = 0;
  for (; b + 2 <= nbat; b += 2) {
    const int eA = b << 3, eB = eA + 8;
    ushort8 idxA = *(const ushort8*)&csru[base + eA];
    ushort8 idxB = *(const ushort8*)&csru[base + eB];
    LOAD8_4(a, idxA)
    LOAD8_4(r, idxB)
    // batch A (index b <= nbat-2) is always full
    addRow(acc, a0); addRow(acc, a1); addRow(acc, a2); addRow(acc, a3);
    addRow(acc, a4); addRow(acc, a5); addRow(acc, a6); addRow(acc, a7);
    if (eB + 8 <= deg) {
      addRow(acc, r0); addRow(acc, r1); addRow(acc, r2); addRow(acc, r3);
      addRow(acc, r4); addRow(acc, r5); addRow(acc, r6); addRow(acc, r7);
    } else {
      addRowM(acc, r0, (eB + 0 < deg) ? 1.f : 0.f);
      addRowM(acc, r1, (eB + 1 < deg) ? 1.f : 0.f);
      addRowM(acc, r2, (eB + 2 < deg) ? 1.f : 0.f);
      addRowM(acc, r3, (eB + 3 < deg) ? 1.f : 0.f);
      addRowM(acc, r4, (eB + 4 < deg) ? 1.f : 0.f);
      addRowM(acc, r5, (eB + 5 < deg) ? 1.f : 0.f);
      addRowM(acc, r6, (eB + 6 < deg) ? 1.f : 0.f);
      addRowM(acc, r7, (eB + 7 < deg) ? 1.f : 0.f);
    }
  }
  if (b < nbat) {  // leftover single batch (possibly partial)
    const int eA = b << 3;
    ushort8 idxA = *(const ushort8*)&csru[base + eA];
    LOAD8_4(a, idxA)
    if (eA + 8 <= deg) {
      addRow(acc, a0); addRow(acc, a1); addRow(acc, a2); addRow(acc, a3);
      addRow(acc, a4); addRow(acc, a5); addRow(acc, a6); addRow(acc, a7);
    } else {
      addRowM(acc, a0, (eA + 0 < deg) ? 1.f : 0.f);
      addRowM(acc, a1, (eA + 1 < deg) ? 1.f : 0.f);
      addRowM(acc, a2, (eA + 2 < deg) ? 1.f : 0.f);
      addRowM(acc, a3, (eA + 3 < deg) ? 1.f : 0.f);
      addRowM(acc, a4, (eA + 4 < deg) ? 1.f : 0.f);
      addRowM(acc, a5, (eA + 5 < deg) ? 1.f : 0.f);
      addRowM(acc, a6, (eA + 6 < deg) ? 1.f : 0.f);
      addRowM(acc, a7, (eA + 7 < deg) ? 1.f : 0.f);
    }
  }

  float dn = rsqrtf((float)(cn + 1));
  float4 bb = *(const float4*)&bias[c4];   // 16B aligned: c4 % 4 == 0
  ushort4 o;
  o.x = f2bf(acc[0] * dn + bb.x);
  o.y = f2bf(acc[1] * dn + bb.y);
  o.z = f2bf(acc[2] * dn + bb.z);
  o.w = f2bf(acc[3] * dn + bb.w);
  *(ushort4*)&aggb[n * H + c4] = o;
}

// ---------------- batchnorm stats over bf16 agg (vectorized ushort8 loads) ----------
// 391 blocks x 128 rows; thread: cg=tid&15 (8 channels), nn=tid>>4 (row in 16-group)
// reduce: shfl over nn-in-wave (x16, x32) -> LDS across 4 waves -> 256 atomics/block
__global__ __launch_bounds__(256) void bn_stats_kernel(
    const ushort_t* __restrict__ a, float* __restrict__ sums)
{
  __shared__ float redS[4 * 128], redQ[4 * 128];
  int tid = threadIdx.x;
  int cg = tid & 15, nn = tid >> 4;
  int c8 = cg * 8;
  int r0 = blockIdx.x * 128;
  float s[8], q[8];
#pragma unroll
  for (int j = 0; j < 8; ++j) { s[j] = 0.f; q[j] = 0.f; }
#pragma unroll
  for (int i = 0; i < 8; ++i) {
    int r = r0 + i * 16 + nn;
    if (r < N) {
      ushort8 u = *(const ushort8*)&a[r * H + c8];
#pragma unroll
      for (int j = 0; j < 8; ++j) { float v = bf2f(u[j]); s[j] += v; q[j] += v * v; }
    }
  }
  int wave = tid >> 6, lane = tid & 63;
#pragma unroll
  for (int j = 0; j < 8; ++j) {
    s[j] += __shfl_xor(s[j], 16); s[j] += __shfl_xor(s[j], 32);
    q[j] += __shfl_xor(q[j], 16); q[j] += __shfl_xor(q[j], 32);
  }
  if (lane < 16) {
#pragma unroll
    for (int j = 0; j < 8; ++j) {
      redS[wave * 128 + lane * 8 + j] = s[j];
      redQ[wave * 128 + lane * 8 + j] = q[j];
    }
  }
  __syncthreads();
  if (tid < 128) {
    float v = redS[tid] + redS[128 + tid] + redS[256 + tid] + redS[384 + tid];
    atomAddF(&sums[tid], v);
  } else {
    int t2 = tid - 128;
    float v = redQ[t2] + redQ[128 + t2] + redQ[256 + t2] + redQ[384 + t2];
    atomAddF(&sums[128 + t2], v);
  }
}

// ---------------- global mean pool: chunked run-length accumulate (batch sorted) --------
__global__ __launch_bounds__(256) void pool_kernel(
    const ushort_t* __restrict__ h, const int* __restrict__ batch,
    float* __restrict__ pooled /* pre-zeroed */)
{
  int r0 = blockIdx.x * 128;
  int rend = min(r0 + 128, N);
  int c = threadIdx.x & 127, half = threadIdx.x >> 7;
  float acc = 0.f;
  int curg = -1;
  for (int r = r0 + half; r < rend; r += 2) {
    int g = batch[r];
    if (g != curg) {
      if (curg >= 0) atomAddF(&pooled[curg * H + c], acc);
      acc = 0.f; curg = g;
    }
    acc += bf2f(h[r * H + c]);
  }
  if (curg >= 0) atomAddF(&pooled[curg * H + c], acc);
}

// ---------------- head (split, multi-block: latency-hiding via 32-64 blocks) ----------
__global__ void head1_kernel(const float* __restrict__ pooled, const float* __restrict__ cntg,
                             const float* __restrict__ W1, const float* __restrict__ b1,
                             float* __restrict__ z1)
{
  int t = blockIdx.x * 256 + threadIdx.x;  // 8192
  int g = t >> 7, c = t & 127;
  float s = 0.f;
  for (int k = 0; k < H; ++k) s += pooled[g * H + k] * W1[k * H + c];
  z1[t] = s / fmaxf(cntg[g], 1.0f) + b1[c];
}

__global__ void head_bn_kernel(float* __restrict__ z1,
                               const float* __restrict__ gamma, const float* __restrict__ beta)
{
  int c = threadIdx.x;  // 128 threads
  float s = 0.f, q = 0.f;
  for (int g = 0; g < G; ++g) { float v = z1[g * H + c]; s += v; q += v * v; }
  float mu = s / (float)G;
  float var = q / (float)G - mu * mu;
  float rs = rsqrtf(var + EPS);
  float ga = gamma[c], be = beta[c];
  for (int g = 0; g < G; ++g) {
    float v = z1[g * H + c];
    z1[g * H + c] = fmaxf((v - mu) * rs * ga + be, 0.f);
  }
}

__global__ void head2_kernel(const float* __restrict__ z1, const float* __restrict__ W2,
                             const float* __restrict__ b2, float* __restrict__ z2)
{
  int t = blockIdx.x * 256 + threadIdx.x;  // 8192
  int g = t >> 7, c = t & 127;
  float s = b2[c];
  for (int k = 0; k < H; ++k) s += z1[g * H + k] * W2[k * H + c];
  z2[t] = fmaxf(s, 0.f);
}

__global__ void head3_kernel(const float* __restrict__ z2, const float* __restrict__ W3,
                             const float* __restrict__ b3, float* __restrict__ out)
{
  int t = blockIdx.x * 256 + threadIdx.x;
  if (t < G * OUTC) {
    int g = t / OUTC, o = t % OUTC;
    float s = b3[o];
    for (int k = 0; k < H; ++k) s += z2[g * H + k] * W3[k * OUTC + o];
    out[t] = s;
  }
}

extern "C" void kernel_launch(void* const* d_in, const int* in_sizes, int n_in,
                              void* d_out, int out_size, void* d_ws, size_t ws_size,
                              hipStream_t stream) {
  const float* x     = (const float*)d_in[0];
  const int*   ei    = (const int*)d_in[1];
  const int*   srcp  = ei;
  const int*   dstp  = ei + E;
  const int*   batch = (const int*)d_in[2];
  const float* convW = (const float*)d_in[3];
  const float* convb = (const float*)d_in[4];
  const float* bng   = (const float*)d_in[5];
  const float* bnb   = (const float*)d_in[6];
  const float* W1    = (const float*)d_in[7];
  const float* b1    = (const float*)d_in[8];
  const float* hg    = (const float*)d_in[9];
  const float* hb    = (const float*)d_in[10];
  const float* W2    = (const float*)d_in[11];
  const float* b2    = (const float*)d_in[12];
  const float* W3    = (const float*)d_in[13];
  const float* b3    = (const float*)d_in[14];
  float* out = (float*)d_out;

  const size_t NH2 = (size_t)N * H / 2;            // bf16 buffer size in float units
  float*    ws     = (float*)d_ws;
  ushort_t* aggb   = (ushort_t*)ws;                // N*H bf16  (16B aligned)
  ushort_t* hWs    = (ushort_t*)(ws + NH2);        // N*H bf16
  ushort_t* WT     = (ushort_t*)(ws + 2 * NH2);    // L*H*H bf16 (49152 floats)
  ushort_t* csru   = (ushort_t*)(ws + 2 * NH2 + (L * H * H / 2));  // N*SLOTS ushort
  int*      cnt    = (int*)(csru + (size_t)N * SLOTS); // N   <- zero region start
  float*    bnsums = (float*)(cnt + N);            // (L-1)*256
  float*    pooled = bnsums + (L - 1) * 256;       // G*H <- zero region end
  float*    cntg   = pooled + G * H;               // G
  float*    z1     = cntg + G;                     // G*H
  float*    z2     = z1 + G * H;                   // G*H

  const int zero_words = N + (L - 1) * 256 + G * H;
  const int ZB = (zero_words + 255) / 256;
  const int PB = (L * H * H) / 256;   // 384, exact
  init_kernel<<<ZB + PB + 1, 256, 0, stream>>>(cnt, zero_words, ZB, convW, WT, batch, cntg);

  const int PHN = (N + NPHASE - 1) / NPHASE;   // 12500 nodes per phase
  for (int p = 0; p < NPHASE; ++p)
    csr_fill_phase_kernel<<<(E + 255) / 256, 256, 0, stream>>>(
        srcp, dstp, cnt, csru, p * PHN, min((p + 1) * PHN, N));

  for (int l = 0; l < L; ++l) {
    const ushort_t* Ab = (l == 0) ? nullptr : aggb;
    const float*    Af = (l == 0) ? x : nullptr;
    const float* bs = (l == 0) ? nullptr : bnsums + (l - 1) * 256;
    const float* ga = (l == 0) ? nullptr : bng + (size_t)(l - 1) * H;
    const float* be = (l == 0) ? nullptr : bnb + (size_t)(l - 1) * H;
    gemm_mfma_kernel<<<(N + 63) / 64, 256, 0, stream>>>(
        Ab, Af, WT + (size_t)l * H * H, cnt, hWs, bs, ga, be);
    gather_kernel<<<N * 32 / 256, 256, 0, stream>>>(
        hWs, csru, cnt, convb + (size_t)l * H, aggb);
    if (l < L - 1)
      bn_stats_kernel<<<(N + 127) / 128, 256, 0, stream>>>(aggb, bnsums + l * 256);
  }

  pool_kernel<<<(N + 127) / 128, 256, 0, stream>>>(aggb, batch, pooled);
  head1_kernel<<<32, 256, 0, stream>>>(pooled, cntg, W1, b1, z1);
  head_bn_kernel<<<1, 128, 0, stream>>>(z1, hg, hb);
  head2_kernel<<<32, 256, 0, stream>>>(z1, W2, b2, z2);
  head3_kernel<<<3, 256, 0, stream>>>(z2, W3, b3, out);
}

// Round 12
// 580.922 us; speedup vs baseline: 1.2400x; 1.0121x over previous
//
#include <hip/hip_runtime.h>

#define N 50000
#define E 800000
#define H 128
#define G 64
#define OUTC 10
#define L 6
#define EPS 1e-5f
#define SLOTS 64   // fixed bucket capacity; deg ~ Poisson(16), P(deg>64) ~ 2e-18

typedef unsigned short ushort_t;
typedef __attribute__((ext_vector_type(8))) short short8;
typedef __attribute__((ext_vector_type(8))) unsigned short ushort8;
typedef __attribute__((ext_vector_type(4))) float floatx4;

__device__ __forceinline__ void atomAddF(float* p, float v) {
  unsafeAtomicAdd(p, v);   // hw global_atomic_add_f32 on gfx950
}

__device__ __forceinline__ unsigned short f2bf(float f) {
  unsigned u = __float_as_uint(f);
  unsigned r = (u + 0x7FFF + ((u >> 16) & 1)) >> 16;  // RNE
  return (unsigned short)r;
}
__device__ __forceinline__ float bf2f(unsigned short b) {
  return __uint_as_float(((unsigned)b) << 16);
}

// ---------------- merged init: zero | weight-transpose prep | graph counts ----------
// block ranges: [0, ZB) zero, [ZB, ZB+PB) prep, last block = cnt binary search
__global__ __launch_bounds__(256) void init_kernel(
    int* __restrict__ zerop, int zero_words, int ZB,
    const float* __restrict__ convW, ushort_t* __restrict__ WT,
    const int* __restrict__ batch, float* __restrict__ cntg)
{
  __shared__ int lb[G + 1];
  int b = blockIdx.x;
  if (b < ZB) {
    int i = b * 256 + threadIdx.x;
    if (i < zero_words) zerop[i] = 0;
  } else if (b < ZB + (L * H * H) / 256) {
    int j = (b - ZB) * 256 + threadIdx.x;   // j < L*H*H (exact multiple of 256)
    int l = j >> 14, r = j & 16383;         // H*H = 16384
    int n = r >> 7, k = r & 127;
    WT[j] = f2bf(convW[l * 16384 + k * 128 + n]);
  } else {
    int t = threadIdx.x;
    if (t <= G) {
      int lo = 0, hi = N;
      while (lo < hi) { int m = (lo + hi) >> 1; if (batch[m] < t) lo = m + 1; else hi = m; }
      lb[t] = lo;
    }
    __syncthreads();
    if (t < G) cntg[t] = (float)(lb[t + 1] - lb[t]);
  }
}

// one-pass bucket CSR build (ushort entries).
// ATOMIC-FLOORED ~50us: 3 probes (cnt-padding null, ushort marginal, dst-phasing
// neutral) => traffic = 1 memory-side line-event per edge, irreducible here.
__global__ void csr_fill_kernel(const int* __restrict__ src, const int* __restrict__ dst,
                                int* __restrict__ cnt, ushort_t* __restrict__ csru) {
  int e = blockIdx.x * blockDim.x + threadIdx.x;
  if (e < E) {
    int d = dst[e];
    int pos = atomicAdd(&cnt[d], 1);
    if (pos < SLOTS) csru[(d << 6) + pos] = (ushort_t)src[e];
  }
}

// ---------------- MFMA GEMM: hWs[row] = dinv[row] * (f(A)@W)[row], bf16 ----------------
// OPERAND-SWAPPED: mfma(Wfrag, nodefrag) -> D[ch][node]; each thread holds 4
// CONSECUTIVE channels of ONE node -> ushort4 (8B) stores, 8 per thread.
// dinv inlined: dv = rsqrt(cnt[node]+1).
// A source: Af (f32, layer 0) or Ab (bf16, layers 1..5); f = identity or BN+ReLU.
__global__ __launch_bounds__(256) void gemm_mfma_kernel(
    const ushort_t* __restrict__ Ab, const float* __restrict__ Af,
    const ushort_t* __restrict__ WT,
    const int* __restrict__ cnt, ushort_t* __restrict__ hWs,
    const float* __restrict__ bnsums, const float* __restrict__ gamma,
    const float* __restrict__ beta)
{
  const int tid = threadIdx.x;
  const int wave = tid >> 6, lane = tid & 63;
  const int quad = lane >> 4, m = lane & 15;
  const int row0 = blockIdx.x * 64 + wave * 16;
  const int arow = min(row0 + m, N - 1);
  const float invN = 1.0f / (float)N;

  short8 nfrag[4];   // node-row fragments (B operand after swap)
  if (Af) {
    // layer 0: read f32 x directly, convert RNE in-register
#pragma unroll
    for (int kc = 0; kc < 4; ++kc) {
      const float* p = &Af[arow * H + kc * 32 + quad * 8];
      float4 f0 = *(const float4*)p;
      float4 f1 = *(const float4*)(p + 4);
      short8 a;
      a[0] = (short)f2bf(f0.x); a[1] = (short)f2bf(f0.y);
      a[2] = (short)f2bf(f0.z); a[3] = (short)f2bf(f0.w);
      a[4] = (short)f2bf(f1.x); a[5] = (short)f2bf(f1.y);
      a[6] = (short)f2bf(f1.z); a[7] = (short)f2bf(f1.w);
      nfrag[kc] = a;
    }
  } else {
#pragma unroll
    for (int kc = 0; kc < 4; ++kc) {
      ushort8 raw = *(const ushort8*)&Ab[arow * H + kc * 32 + quad * 8];
      if (bnsums) {
        const int k0 = kc * 32 + quad * 8;
#pragma unroll
        for (int j = 0; j < 8; ++j) {
          float s = bnsums[k0 + j], q = bnsums[128 + k0 + j];
          float mu = s * invN;
          float var = q * invN - mu * mu;
          float rs = rsqrtf(var + EPS);
          float sc = gamma[k0 + j] * rs;
          float sh = beta[k0 + j] - mu * sc;
          raw[j] = f2bf(fmaxf(bf2f(raw[j]) * sc + sh, 0.f));
        }
      }
      short8 a;
#pragma unroll
      for (int j = 0; j < 8; ++j) a[j] = (short)raw[j];
      nfrag[kc] = a;
    }
  }

  const int node = row0 + m;
  const float dv = (node < N) ? rsqrtf((float)(cnt[node] + 1)) : 0.f;

  const short* WTs = (const short*)WT;
#pragma unroll
  for (int nt = 0; nt < 8; ++nt) {
    floatx4 acc = {0.f, 0.f, 0.f, 0.f};
#pragma unroll
    for (int kc = 0; kc < 4; ++kc) {
      short8 wfrag = *(const short8*)&WTs[(nt * 16 + m) * H + kc * 32 + quad * 8];
      acc = __builtin_amdgcn_mfma_f32_16x16x32_bf16(wfrag, nfrag[kc], acc, 0, 0, 0);
    }
    // D[ch = nt*16 + quad*4 + i][node = lane&15]
    if (node < N) {
      ushort4 o;
      o.x = f2bf(acc[0] * dv);
      o.y = f2bf(acc[1] * dv);
      o.z = f2bf(acc[2] * dv);
      o.w = f2bf(acc[3] * dv);
      *(ushort4*)&hWs[node * H + nt * 16 + quad * 4] = o;   // 8B aligned
    }
  }
}

// ---------------- CSR gather, 32 lanes/node + 2-batch software pipeline -------------
// DATA-PATH FLOOR ~35us/layer: 2 probes (TLP-doubling marginal, L2-chunking
// regressed) => ~205MB/layer of scattered row reads at ~6 TB/s effective.
// aggb[n] = bf16( dinv[n]*(sum_e hWs[src_e] + hWs[n]) + bias ), dinv inlined.
// 32 lanes per node, 4 channels (ushort4 = 8B) per lane; grid exact (N*32/256).
__device__ __forceinline__ void addRow(float acc[4], ushort4 u) {
  acc[0] += bf2f(u.x); acc[1] += bf2f(u.y);
  acc[2] += bf2f(u.z); acc[3] += bf2f(u.w);
}
__device__ __forceinline__ void addRowM(float acc[4], ushort4 u, float m) {
  acc[0] += m * bf2f(u.x); acc[1] += m * bf2f(u.y);
  acc[2] += m * bf2f(u.z); acc[3] += m * bf2f(u.w);
}

#define LOAD8_4(dst, idx)                                           \
  ushort4 dst##0 = *(const ushort4*)&hWs[(int)idx[0] * H + c4];     \
  ushort4 dst##1 = *(const ushort4*)&hWs[(int)idx[1] * H + c4];     \
  ushort4 dst##2 = *(const ushort4*)&hWs[(int)idx[2] * H + c4];     \
  ushort4 dst##3 = *(const ushort4*)&hWs[(int)idx[3] * H + c4];     \
  ushort4 dst##4 = *(const ushort4*)&hWs[(int)idx[4] * H + c4];     \
  ushort4 dst##5 = *(const ushort4*)&hWs[(int)idx[5] * H + c4];     \
  ushort4 dst##6 = *(const ushort4*)&hWs[(int)idx[6] * H + c4];     \
  ushort4 dst##7 = *(const ushort4*)&hWs[(int)idx[7] * H + c4];

__global__ __launch_bounds__(256) void gather_kernel(
    const ushort_t* __restrict__ hWs, const ushort_t* __restrict__ csru,
    const int* __restrict__ cnt,
    const float* __restrict__ bias, ushort_t* __restrict__ aggb)
{
  int t = blockIdx.x * 256 + threadIdx.x;
  int n = t >> 5, c4 = (t & 31) * 4;

  const int base = n << 6;
  const int cn = cnt[n];
  const int deg = min(cn, SLOTS);

  ushort4 us = *(const ushort4*)&hWs[n * H + c4];
  float acc[4];
  acc[0] = bf2f(us.x); acc[1] = bf2f(us.y);
  acc[2] = bf2f(us.z); acc[3] = bf2f(us.w);

  const int nbat = (deg + 7) >> 3;   // 0..8 batches; only last batch partial
  int b = 0;
  for (; b + 2 <= nbat; b += 2) {
    const int eA = b << 3, eB = eA + 8;
    ushort8 idxA = *(const ushort8*)&csru[base + eA];
    ushort8 idxB = *(const ushort8*)&csru[base + eB];
    LOAD8_4(a, idxA)
    LOAD8_4(r, idxB)
    // batch A (index b <= nbat-2) is always full
    addRow(acc, a0); addRow(acc, a1); addRow(acc, a2); addRow(acc, a3);
    addRow(acc, a4); addRow(acc, a5); addRow(acc, a6); addRow(acc, a7);
    if (eB + 8 <= deg) {
      addRow(acc, r0); addRow(acc, r1); addRow(acc, r2); addRow(acc, r3);
      addRow(acc, r4); addRow(acc, r5); addRow(acc, r6); addRow(acc, r7);
    } else {
      addRowM(acc, r0, (eB + 0 < deg) ? 1.f : 0.f);
      addRowM(acc, r1, (eB + 1 < deg) ? 1.f : 0.f);
      addRowM(acc, r2, (eB + 2 < deg) ? 1.f : 0.f);
      addRowM(acc, r3, (eB + 3 < deg) ? 1.f : 0.f);
      addRowM(acc, r4, (eB + 4 < deg) ? 1.f : 0.f);
      addRowM(acc, r5, (eB + 5 < deg) ? 1.f : 0.f);
      addRowM(acc, r6, (eB + 6 < deg) ? 1.f : 0.f);
      addRowM(acc, r7, (eB + 7 < deg) ? 1.f : 0.f);
    }
  }
  if (b < nbat) {  // leftover single batch (possibly partial)
    const int eA = b << 3;
    ushort8 idxA = *(const ushort8*)&csru[base + eA];
    LOAD8_4(a, idxA)
    if (eA + 8 <= deg) {
      addRow(acc, a0); addRow(acc, a1); addRow(acc, a2); addRow(acc, a3);
      addRow(acc, a4); addRow(acc, a5); addRow(acc, a6); addRow(acc, a7);
    } else {
      addRowM(acc, a0, (eA + 0 < deg) ? 1.f : 0.f);
      addRowM(acc, a1, (eA + 1 < deg) ? 1.f : 0.f);
      addRowM(acc, a2, (eA + 2 < deg) ? 1.f : 0.f);
      addRowM(acc, a3, (eA + 3 < deg) ? 1.f : 0.f);
      addRowM(acc, a4, (eA + 4 < deg) ? 1.f : 0.f);
      addRowM(acc, a5, (eA + 5 < deg) ? 1.f : 0.f);
      addRowM(acc, a6, (eA + 6 < deg) ? 1.f : 0.f);
      addRowM(acc, a7, (eA + 7 < deg) ? 1.f : 0.f);
    }
  }

  float dn = rsqrtf((float)(cn + 1));
  float4 bb = *(const float4*)&bias[c4];   // 16B aligned: c4 % 4 == 0
  ushort4 o;
  o.x = f2bf(acc[0] * dn + bb.x);
  o.y = f2bf(acc[1] * dn + bb.y);
  o.z = f2bf(acc[2] * dn + bb.z);
  o.w = f2bf(acc[3] * dn + bb.w);
  *(ushort4*)&aggb[n * H + c4] = o;
}

// ---------------- batchnorm stats over bf16 agg (vectorized ushort8 loads) ----------
// 391 blocks x 128 rows; thread: cg=tid&15 (8 channels), nn=tid>>4 (row in 16-group)
// reduce: shfl over nn-in-wave (x16, x32) -> LDS across 4 waves -> 256 atomics/block
__global__ __launch_bounds__(256) void bn_stats_kernel(
    const ushort_t* __restrict__ a, float* __restrict__ sums)
{
  __shared__ float redS[4 * 128], redQ[4 * 128];
  int tid = threadIdx.x;
  int cg = tid & 15, nn = tid >> 4;
  int c8 = cg * 8;
  int r0 = blockIdx.x * 128;
  float s[8], q[8];
#pragma unroll
  for (int j = 0; j < 8; ++j) { s[j] = 0.f; q[j] = 0.f; }
#pragma unroll
  for (int i = 0; i < 8; ++i) {
    int r = r0 + i * 16 + nn;
    if (r < N) {
      ushort8 u = *(const ushort8*)&a[r * H + c8];
#pragma unroll
      for (int j = 0; j < 8; ++j) { float v = bf2f(u[j]); s[j] += v; q[j] += v * v; }
    }
  }
  int wave = tid >> 6, lane = tid & 63;
#pragma unroll
  for (int j = 0; j < 8; ++j) {
    s[j] += __shfl_xor(s[j], 16); s[j] += __shfl_xor(s[j], 32);
    q[j] += __shfl_xor(q[j], 16); q[j] += __shfl_xor(q[j], 32);
  }
  if (lane < 16) {
#pragma unroll
    for (int j = 0; j < 8; ++j) {
      redS[wave * 128 + lane * 8 + j] = s[j];
      redQ[wave * 128 + lane * 8 + j] = q[j];
    }
  }
  __syncthreads();
  if (tid < 128) {
    float v = redS[tid] + redS[128 + tid] + redS[256 + tid] + redS[384 + tid];
    atomAddF(&sums[tid], v);
  } else {
    int t2 = tid - 128;
    float v = redQ[t2] + redQ[128 + t2] + redQ[256 + t2] + redQ[384 + t2];
    atomAddF(&sums[128 + t2], v);
  }
}

// ---------------- global mean pool: chunked run-length accumulate (batch sorted) --------
__global__ __launch_bounds__(256) void pool_kernel(
    const ushort_t* __restrict__ h, const int* __restrict__ batch,
    float* __restrict__ pooled /* pre-zeroed */)
{
  int r0 = blockIdx.x * 128;
  int rend = min(r0 + 128, N);
  int c = threadIdx.x & 127, half = threadIdx.x >> 7;
  float acc = 0.f;
  int curg = -1;
  for (int r = r0 + half; r < rend; r += 2) {
    int g = batch[r];
    if (g != curg) {
      if (curg >= 0) atomAddF(&pooled[curg * H + c], acc);
      acc = 0.f; curg = g;
    }
    acc += bf2f(h[r * H + c]);
  }
  if (curg >= 0) atomAddF(&pooled[curg * H + c], acc);
}

// ---------------- head (split, multi-block: latency-hiding via 32-64 blocks) ----------
__global__ void head1_kernel(const float* __restrict__ pooled, const float* __restrict__ cntg,
                             const float* __restrict__ W1, const float* __restrict__ b1,
                             float* __restrict__ z1)
{
  int t = blockIdx.x * 256 + threadIdx.x;  // 8192
  int g = t >> 7, c = t & 127;
  float s = 0.f;
  for (int k = 0; k < H; ++k) s += pooled[g * H + k] * W1[k * H + c];
  z1[t] = s / fmaxf(cntg[g], 1.0f) + b1[c];
}

__global__ void head_bn_kernel(float* __restrict__ z1,
                               const float* __restrict__ gamma, const float* __restrict__ beta)
{
  int c = threadIdx.x;  // 128 threads
  float s = 0.f, q = 0.f;
  for (int g = 0; g < G; ++g) { float v = z1[g * H + c]; s += v; q += v * v; }
  float mu = s / (float)G;
  float var = q / (float)G - mu * mu;
  float rs = rsqrtf(var + EPS);
  float ga = gamma[c], be = beta[c];
  for (int g = 0; g < G; ++g) {
    float v = z1[g * H + c];
    z1[g * H + c] = fmaxf((v - mu) * rs * ga + be, 0.f);
  }
}

__global__ void head2_kernel(const float* __restrict__ z1, const float* __restrict__ W2,
                             const float* __restrict__ b2, float* __restrict__ z2)
{
  int t = blockIdx.x * 256 + threadIdx.x;  // 8192
  int g = t >> 7, c = t & 127;
  float s = b2[c];
  for (int k = 0; k < H; ++k) s += z1[g * H + k] * W2[k * H + c];
  z2[t] = fmaxf(s, 0.f);
}

__global__ void head3_kernel(const float* __restrict__ z2, const float* __restrict__ W3,
                             const float* __restrict__ b3, float* __restrict__ out)
{
  int t = blockIdx.x * 256 + threadIdx.x;
  if (t < G * OUTC) {
    int g = t / OUTC, o = t % OUTC;
    float s = b3[o];
    for (int k = 0; k < H; ++k) s += z2[g * H + k] * W3[k * OUTC + o];
    out[t] = s;
  }
}

extern "C" void kernel_launch(void* const* d_in, const int* in_sizes, int n_in,
                              void* d_out, int out_size, void* d_ws, size_t ws_size,
                              hipStream_t stream) {
  const float* x     = (const float*)d_in[0];
  const int*   ei    = (const int*)d_in[1];
  const int*   srcp  = ei;
  const int*   dstp  = ei + E;
  const int*   batch = (const int*)d_in[2];
  const float* convW = (const float*)d_in[3];
  const float* convb = (const float*)d_in[4];
  const float* bng   = (const float*)d_in[5];
  const float* bnb   = (const float*)d_in[6];
  const float* W1    = (const float*)d_in[7];
  const float* b1    = (const float*)d_in[8];
  const float* hg    = (const float*)d_in[9];
  const float* hb    = (const float*)d_in[10];
  const float* W2    = (const float*)d_in[11];
  const float* b2    = (const float*)d_in[12];
  const float* W3    = (const float*)d_in[13];
  const float* b3    = (const float*)d_in[14];
  float* out = (float*)d_out;

  const size_t NH2 = (size_t)N * H / 2;            // bf16 buffer size in float units
  float*    ws     = (float*)d_ws;
  ushort_t* aggb   = (ushort_t*)ws;                // N*H bf16  (16B aligned)
  ushort_t* hWs    = (ushort_t*)(ws + NH2);        // N*H bf16
  ushort_t* WT     = (ushort_t*)(ws + 2 * NH2);    // L*H*H bf16 (49152 floats)
  ushort_t* csru   = (ushort_t*)(ws + 2 * NH2 + (L * H * H / 2));  // N*SLOTS ushort
  int*      cnt    = (int*)(csru + (size_t)N * SLOTS); // N   <- zero region start
  float*    bnsums = (float*)(cnt + N);            // (L-1)*256
  float*    pooled = bnsums + (L - 1) * 256;       // G*H <- zero region end
  float*    cntg   = pooled + G * H;               // G
  float*    z1     = cntg + G;                     // G*H
  float*    z2     = z1 + G * H;                   // G*H

  const int zero_words = N + (L - 1) * 256 + G * H;
  const int ZB = (zero_words + 255) / 256;
  const int PB = (L * H * H) / 256;   // 384, exact
  init_kernel<<<ZB + PB + 1, 256, 0, stream>>>(cnt, zero_words, ZB, convW, WT, batch, cntg);
  csr_fill_kernel<<<(E + 255) / 256, 256, 0, stream>>>(srcp, dstp, cnt, csru);

  for (int l = 0; l < L; ++l) {
    const ushort_t* Ab = (l == 0) ? nullptr : aggb;
    const float*    Af = (l == 0) ? x : nullptr;
    const float* bs = (l == 0) ? nullptr : bnsums + (l - 1) * 256;
    const float* ga = (l == 0) ? nullptr : bng + (size_t)(l - 1) * H;
    const float* be = (l == 0) ? nullptr : bnb + (size_t)(l - 1) * H;
    gemm_mfma_kernel<<<(N + 63) / 64, 256, 0, stream>>>(
        Ab, Af, WT + (size_t)l * H * H, cnt, hWs, bs, ga, be);
    gather_kernel<<<N * 32 / 256, 256, 0, stream>>>(
        hWs, csru, cnt, convb + (size_t)l * H, aggb);
    if (l < L - 1)
      bn_stats_kernel<<<(N + 127) / 128, 256, 0, stream>>>(aggb, bnsums + l * 256);
  }

  pool_kernel<<<(N + 127) / 128, 256, 0, stream>>>(aggb, batch, pooled);
  head1_kernel<<<32, 256, 0, stream>>>(pooled, cntg, W1, b1, z1);
  head_bn_kernel<<<1, 128, 0, stream>>>(z1, hg, hb);
  head2_kernel<<<32, 256, 0, stream>>>(z1, W2, b2, z2);
  head3_kernel<<<3, 256, 0, stream>>>(z2, W3, b3, out);
}